// Round 6
// baseline (287.894 us; speedup 1.0000x reference)
//
#include <hip/hip_runtime.h>
#include <hip/hip_bf16.h>
#include <stdint.h>

#define DEV static __device__ __forceinline__

typedef float f32x4 __attribute__((ext_vector_type(4)));
typedef int   i32x4 __attribute__((ext_vector_type(4)));
typedef unsigned short u16x4 __attribute__((ext_vector_type(4)));
typedef __bf16 bf16x8 __attribute__((ext_vector_type(8)));

constexpr int Bb = 4, Ss = 2048, Ee = 512, Hh = 8, Dd = 64;
constexpr float LOG2E = 1.4426950408889634f;

DEV unsigned short f2bf(float f) {  // RNE f32->bf16 (no NaN path needed)
  unsigned u = __float_as_uint(f);
  u += 0x7fff + ((u >> 16) & 1);
  return (unsigned short)(u >> 16);
}
DEV float bf2f(unsigned short h) { return __uint_as_float(((unsigned)h) << 16); }

DEV void gload16(const void* g, void* l) {
  __builtin_amdgcn_global_load_lds((__attribute__((address_space(1))) void*)(g),
                                   (__attribute__((address_space(3))) void*)(l), 16, 0, 0);
}

// ---------------- converts ----------------
__global__ void k_cvt(const float* __restrict__ src, unsigned short* __restrict__ dst, int n4) {
  int i = blockIdx.x * 256 + threadIdx.x;
  if (i >= n4) return;
  f32x4 v = *(const f32x4*)(src + (size_t)i * 4);
  u16x4 o;
#pragma unroll
  for (int j = 0; j < 4; ++j) o[j] = f2bf(v[j]);
  *(u16x4*)(dst + (size_t)i * 4) = o;
}

// bias*log2e, masked -> -1.44e38 (exp2-domain softmax)
__global__ void k_mb(const float* __restrict__ bias, const int* __restrict__ mask,
                     unsigned short* __restrict__ mb, int n4) {
  int i = blockIdx.x * 256 + threadIdx.x;
  if (i >= n4) return;
  f32x4 v = *(const f32x4*)(bias + (size_t)i * 4);
  i32x4 m = *(const i32x4*)(mask + (size_t)i * 4);
  u16x4 o;
  const unsigned short NEG = f2bf(-1e38f * LOG2E);
#pragma unroll
  for (int j = 0; j < 4; ++j) o[j] = m[j] ? f2bf(v[j] * LOG2E) : NEG;
  *(u16x4*)(mb + (size_t)i * 4) = o;
}

// ---------------- GEMM (A[M][512] x Bw[N][512]^T), 128x128 tile, BK=32 ----------------
template <int MODE>
__global__ __launch_bounds__(256) void k_gemm(
    const unsigned short* __restrict__ A, const unsigned short* __restrict__ Bw,
    const float* __restrict__ b0, const float* __restrict__ b1, const float* __restrict__ b2,
    unsigned short* __restrict__ oq, unsigned short* __restrict__ ok,
    unsigned short* __restrict__ ovt, float* __restrict__ of32) {
  __shared__ unsigned short Asl[128 * 32];
  __shared__ unsigned short Bsl[128 * 32];
  const int tid = threadIdx.x;
  const int wave = tid >> 6, lane = tid & 63;
  const int l15 = lane & 15, lg = lane >> 4;
  const int brow = blockIdx.x, bcol = blockIdx.y;
  const int wm = (wave >> 1) * 64, wn = (wave & 1) * 64;

  f32x4 acc[4][4] = {};

  for (int k0 = 0; k0 < 512; k0 += 32) {
    __syncthreads();
#pragma unroll
    for (int rnd = 0; rnd < 2; ++rnd) {
      int vid = rnd * 256 + tid;
      int r = vid >> 2, c = vid & 3;
      gload16(A + (size_t)(brow * 128 + r) * 512 + k0 + c * 8,
              Asl + (size_t)(rnd * 256 + wave * 64) * 8);
      gload16(Bw + (size_t)(bcol * 128 + r) * 512 + k0 + c * 8,
              Bsl + (size_t)(rnd * 256 + wave * 64) * 8);
    }
    __syncthreads();
    bf16x8 af[4], bfr[4];
#pragma unroll
    for (int m = 0; m < 4; ++m) af[m] = *(const bf16x8*)(Asl + (wm + m * 16 + l15) * 32 + lg * 8);
#pragma unroll
    for (int n = 0; n < 4; ++n) bfr[n] = *(const bf16x8*)(Bsl + (wn + n * 16 + l15) * 32 + lg * 8);
#pragma unroll
    for (int m = 0; m < 4; ++m)
#pragma unroll
      for (int n = 0; n < 4; ++n)
        acc[m][n] = __builtin_amdgcn_mfma_f32_16x16x32_bf16(af[m], bfr[n], acc[m][n], 0, 0, 0);
  }

  if (MODE == 0) {
    const int Nbase = bcol * 128;
    const int mat = Nbase >> 9;        // 0=q,1=k,2=v (uniform per block)
    const int colb = Nbase & 511;
    const float* bp = (mat == 0) ? b0 : ((mat == 1) ? b1 : b2);
#pragma unroll
    for (int m = 0; m < 4; ++m)
#pragma unroll
      for (int n = 0; n < 4; ++n) {
        const int col = colb + wn + n * 16 + l15;
        const int h = col >> 6, d = col & 63;
        const float bv = bp[col];
#pragma unroll
        for (int j = 0; j < 4; ++j) {
          const int M = brow * 128 + wm + m * 16 + lg * 4 + j;
          const int b = M >> 11, s = M & 2047;
          float outv = acc[m][n][j] + bv;
          if (mat == 0) outv *= 0.125f * LOG2E;  // softmax scale * log2e folded into q
          const unsigned short hv = f2bf(outv);
          if (mat == 0)
            oq[(((size_t)(b * Hh + h)) * Ss + s) * Dd + d] = hv;
          else if (mat == 1)
            ok[(((size_t)(b * Hh + h)) * Ss + s) * Dd + d] = hv;
          else
            ovt[(((size_t)(b * Hh + h)) * Dd + d) * Ss + s] = hv;  // V transposed
        }
      }
  } else {
#pragma unroll
    for (int m = 0; m < 4; ++m)
#pragma unroll
      for (int n = 0; n < 4; ++n) {
        const int col = bcol * 128 + wn + n * 16 + l15;
        const float bv = b0[col];
#pragma unroll
        for (int j = 0; j < 4; ++j) {
          const int M = brow * 128 + wm + m * 16 + lg * 4 + j;
          of32[(size_t)M * 512 + col] = acc[m][n][j] + bv;
        }
      }
  }
}

// ---------------- flash attention v4: swapped-QK^T + direct-V issued EARLY ----------
// grid (32,32), 4 waves x 16 q-rows. Lane: q = l15 (uniform), holds 16 key-scores.
// Issue order per iter: V(global)+bias FIRST, then sched_barrier, then K prefetch
// (gload_lds) -> bias-use waits only on stage count, V covered by QK phase,
// K prefetch drains only at the next __syncthreads (r4 discipline).
__global__ __launch_bounds__(256, 4) void k_attn(
    const unsigned short* __restrict__ q, const unsigned short* __restrict__ k,
    const unsigned short* __restrict__ vt, const unsigned short* __restrict__ mb,
    unsigned short* __restrict__ att) {
  __shared__ unsigned short Ksl[2][4096];
  __shared__ unsigned short Psl[4][1024];  // per-wave [16 q][64 key], XOR-swizzled
  const int tid = threadIdx.x;
  const int wave = tid >> 6, lane = tid & 63;
  const int l15 = lane & 15, lg = lane >> 4;
  const int qt = blockIdx.x, bh = blockIdx.y;
  const int b = bh >> 3, h = bh & 7;
  const size_t qkb = (size_t)bh * Ss * Dd;
  const size_t vtbase = (size_t)bh * Dd * Ss;
  const int q0 = qt * 64 + wave * 16;
  const int qrow = q0 + l15;
  const int swz = (l15 & 7) << 3;  // u16-index XOR (16B granules)

  bf16x8 qf[2];  // Q row (pre-scaled by 0.125*log2e)
#pragma unroll
  for (int ks = 0; ks < 2; ++ks)
    qf[ks] = *(const bf16x8*)(q + qkb + (size_t)qrow * Dd + ks * 32 + lg * 8);

  const size_t mbrow = ((size_t)b * Ss + qrow) * Ss;  // bias row base (log2-domain)

  f32x4 accO[4] = {};       // [d-block n][j]: d = n*16+lg*4+j, col q = l15
  float mrow = -INFINITY, lrow = 0.f;

  auto stageK = [&](int buf, int t) {
#pragma unroll
    for (int rnd = 0; rnd < 2; ++rnd) {
      int v2 = rnd * 256 + tid;
      int ks = v2 >> 8, r = (v2 >> 2) & 63, c = v2 & 3;
      gload16(k + qkb + (size_t)(t * 64 + r) * Dd + ks * 32 + c * 8,
              &Ksl[buf][(rnd * 256 + wave * 64) * 8]);
    }
  };
  stageK(0, 0);

  for (int t = 0; t < 32; ++t) {
    const int cur = t & 1;
    const int key0 = t * 64;
    __syncthreads();  // K(t) staged (vmcnt drained here); buf[cur^1] reads done

    // V direct from global (L2-resident) — issued FIRST, consumed at PV (~400cy)
    bf16x8 vtf[2][4];
#pragma unroll
    for (int ks2 = 0; ks2 < 2; ++ks2)
#pragma unroll
      for (int n = 0; n < 4; ++n)
        vtf[ks2][n] = *(const bf16x8*)(vt + vtbase + (size_t)(n * 16 + l15) * Ss +
                                       key0 + ks2 * 32 + lg * 8);

    // bias: 4x 8B loads (lane: q=l15 row, keys m*16+lg*4..+3)
    u16x4 bvv[4];
#pragma unroll
    for (int m = 0; m < 4; ++m)
      bvv[m] = *(const u16x4*)(mb + mbrow + key0 + m * 16 + lg * 4);

    __builtin_amdgcn_sched_barrier(0);  // pin: V+bias issued before K prefetch

    if (t < 31) stageK(cur ^ 1, t + 1);  // in flight until next barrier

    // QK^T swapped: sc[m] rows = keys m*16+lg*4+j, col = q = l15
    f32x4 sc[4] = {};
#pragma unroll
    for (int ks = 0; ks < 2; ++ks) {
      bf16x8 kfm[4];
#pragma unroll
      for (int m = 0; m < 4; ++m)
        kfm[m] = *(const bf16x8*)(&Ksl[cur][ks * 2048 + (m * 16 + l15) * 32 + lg * 8]);
#pragma unroll
      for (int m = 0; m < 4; ++m)
        sc[m] = __builtin_amdgcn_mfma_f32_16x16x32_bf16(kfm[m], qf[ks], sc[m], 0, 0, 0);
    }

    // softmax (exp2 domain), lane-local over 16 keys + 2 shuffles across lg
    float pm = -INFINITY;
#pragma unroll
    for (int m = 0; m < 4; ++m)
#pragma unroll
      for (int j = 0; j < 4; ++j) {
        sc[m][j] += bf2f(bvv[m][j]);
        pm = fmaxf(pm, sc[m][j]);
      }
    pm = fmaxf(pm, __shfl_xor(pm, 16));
    pm = fmaxf(pm, __shfl_xor(pm, 32));
    const float mnew = fmaxf(mrow, pm);
    const float c = exp2f(mrow - mnew);
    mrow = mnew;
    float rs = 0.f;
#pragma unroll
    for (int m = 0; m < 4; ++m)
#pragma unroll
      for (int j = 0; j < 4; ++j) {
        const float p = exp2f(sc[m][j] - mnew);
        sc[m][j] = p;
        rs += p;
      }
    rs += __shfl_xor(rs, 16);
    rs += __shfl_xor(rs, 32);
    lrow = lrow * c + rs;
#pragma unroll
    for (int n = 0; n < 4; ++n) accO[n] *= c;  // c uniform per lane

    // P -> LDS [q=l15][key], swizzled; 4x ds_write_b64
#pragma unroll
    for (int m = 0; m < 4; ++m) {
      u16x4 o;
#pragma unroll
      for (int j = 0; j < 4; ++j) o[j] = f2bf(sc[m][j]);
      *(u16x4*)(&Psl[wave][(l15 * 64 + m * 16 + lg * 4) ^ swz]) = o;
    }
    asm volatile("" ::: "memory");  // pin write->read program order (same-wave LDS in-order)

    // PV swapped: A = Vt[d][k] (regs), B = P[k][q] (LDS); 2x ds_read_b128 + 8 MFMA
#pragma unroll
    for (int ks2 = 0; ks2 < 2; ++ks2) {
      bf16x8 pB = *(const bf16x8*)(&Psl[wave][(l15 * 64 + ks2 * 32 + lg * 8) ^ swz]);
#pragma unroll
      for (int n = 0; n < 4; ++n)
        accO[n] = __builtin_amdgcn_mfma_f32_16x16x32_bf16(vtf[ks2][n], pB, accO[n], 0, 0, 0);
    }
  }

  // epilogue: accO[n][j] = out[d = n*16+lg*4+j][q = l15]
  const float invl = 1.0f / lrow;
#pragma unroll
  for (int n = 0; n < 4; ++n) {
    u16x4 o;
#pragma unroll
    for (int j = 0; j < 4; ++j) o[j] = f2bf(accO[n][j] * invl);
    *(u16x4*)(att + ((size_t)b * Ss + qrow) * Ee + h * Dd + n * 16 + lg * 4) = o;
  }
}

extern "C" void kernel_launch(void* const* d_in, const int* in_sizes, int n_in,
                              void* d_out, int out_size, void* d_ws, size_t ws_size,
                              hipStream_t stream) {
  const float* x  = (const float*)d_in[0];
  const float* eb = (const float*)d_in[1];
  const int*   am = (const int*)d_in[2];
  const float* Wq = (const float*)d_in[3];
  const float* bq = (const float*)d_in[4];
  const float* Wk = (const float*)d_in[5];
  const float* bk = (const float*)d_in[6];
  const float* Wv = (const float*)d_in[7];
  const float* bv = (const float*)d_in[8];
  const float* Wo = (const float*)d_in[9];
  const float* bo = (const float*)d_in[10];
  float* out = (float*)d_out;

  unsigned short* xb   = (unsigned short*)d_ws;              // [8192][512]
  unsigned short* wqkv = xb + (size_t)8192 * 512;            // [1536][512]
  unsigned short* wo   = wqkv + (size_t)1536 * 512;          // [512][512]
  unsigned short* qb   = wo + (size_t)512 * 512;             // [B][H][S][D]
  unsigned short* kb   = qb + (size_t)Bb * Hh * Ss * Dd;     // [B][H][S][D]
  unsigned short* vtb  = kb + (size_t)Bb * Hh * Ss * Dd;     // [B][H][D][S]
  unsigned short* attb = vtb + (size_t)Bb * Hh * Ss * Dd;    // [8192][512]
  unsigned short* mbb  = attb + (size_t)8192 * 512;          // [B][S][S]

  k_cvt<<<4096, 256, 0, stream>>>(x, xb, 8192 * 512 / 4);
  k_cvt<<<256, 256, 0, stream>>>(Wq, wqkv, 512 * 512 / 4);
  k_cvt<<<256, 256, 0, stream>>>(Wk, wqkv + (size_t)512 * 512, 512 * 512 / 4);
  k_cvt<<<256, 256, 0, stream>>>(Wv, wqkv + (size_t)1024 * 512, 512 * 512 / 4);
  k_cvt<<<256, 256, 0, stream>>>(Wo, wo, 512 * 512 / 4);
  k_mb<<<16384, 256, 0, stream>>>(eb, am, mbb, Bb * Ss * Ss / 4);

  dim3 blk(256);
  dim3 g1(64, 12);
  k_gemm<0><<<g1, blk, 0, stream>>>(xb, wqkv, bq, bk, bv, qb, kb, vtb, nullptr);
  dim3 g2(32, 32);
  k_attn<<<g2, blk, 0, stream>>>(qb, kb, vtb, mbb, attb);
  dim3 g3(64, 4);
  k_gemm<1><<<g3, blk, 0, stream>>>(attb, wo, bo, nullptr, nullptr, nullptr, nullptr, nullptr, out);
}

// Round 7
// 186.656 us; speedup vs baseline: 1.5424x; 1.5424x over previous
//
#include <hip/hip_runtime.h>
#include <hip/hip_bf16.h>
#include <stdint.h>

#define DEV static __device__ __forceinline__

typedef float f32x4 __attribute__((ext_vector_type(4)));
typedef int   i32x4 __attribute__((ext_vector_type(4)));
typedef unsigned short u16x4 __attribute__((ext_vector_type(4)));
typedef __bf16 bf16x8 __attribute__((ext_vector_type(8)));

constexpr int Bb = 4, Ss = 2048, Ee = 512, Hh = 8, Dd = 64;
constexpr float LOG2E = 1.4426950408889634f;

DEV unsigned short f2bf(float f) {  // RNE f32->bf16 (no NaN path needed)
  unsigned u = __float_as_uint(f);
  u += 0x7fff + ((u >> 16) & 1);
  return (unsigned short)(u >> 16);
}
DEV float bf2f(unsigned short h) { return __uint_as_float(((unsigned)h) << 16); }

DEV void gload16(const void* g, void* l) {
  __builtin_amdgcn_global_load_lds((__attribute__((address_space(1))) void*)(g),
                                   (__attribute__((address_space(3))) void*)(l), 16, 0, 0);
}

// ---------------- converts ----------------
__global__ void k_cvt(const float* __restrict__ src, unsigned short* __restrict__ dst, int n4) {
  int i = blockIdx.x * 256 + threadIdx.x;
  if (i >= n4) return;
  f32x4 v = *(const f32x4*)(src + (size_t)i * 4);
  u16x4 o;
#pragma unroll
  for (int j = 0; j < 4; ++j) o[j] = f2bf(v[j]);
  *(u16x4*)(dst + (size_t)i * 4) = o;
}

// bias*log2e, masked -> -1.44e38 (exp2-domain softmax)
__global__ void k_mb(const float* __restrict__ bias, const int* __restrict__ mask,
                     unsigned short* __restrict__ mb, int n4) {
  int i = blockIdx.x * 256 + threadIdx.x;
  if (i >= n4) return;
  f32x4 v = *(const f32x4*)(bias + (size_t)i * 4);
  i32x4 m = *(const i32x4*)(mask + (size_t)i * 4);
  u16x4 o;
  const unsigned short NEG = f2bf(-1e38f * LOG2E);
#pragma unroll
  for (int j = 0; j < 4; ++j) o[j] = m[j] ? f2bf(v[j] * LOG2E) : NEG;
  *(u16x4*)(mb + (size_t)i * 4) = o;
}

// ---------------- GEMM (A[M][512] x Bw[N][512]^T), 128x128 tile, BK=32 ----------------
template <int MODE>
__global__ __launch_bounds__(256) void k_gemm(
    const unsigned short* __restrict__ A, const unsigned short* __restrict__ Bw,
    const float* __restrict__ b0, const float* __restrict__ b1, const float* __restrict__ b2,
    unsigned short* __restrict__ oq, unsigned short* __restrict__ ok,
    unsigned short* __restrict__ ovt, float* __restrict__ of32) {
  __shared__ unsigned short Asl[128 * 32];
  __shared__ unsigned short Bsl[128 * 32];
  const int tid = threadIdx.x;
  const int wave = tid >> 6, lane = tid & 63;
  const int l15 = lane & 15, lg = lane >> 4;
  const int brow = blockIdx.x, bcol = blockIdx.y;
  const int wm = (wave >> 1) * 64, wn = (wave & 1) * 64;

  f32x4 acc[4][4] = {};

  for (int k0 = 0; k0 < 512; k0 += 32) {
    __syncthreads();
#pragma unroll
    for (int rnd = 0; rnd < 2; ++rnd) {
      int vid = rnd * 256 + tid;
      int r = vid >> 2, c = vid & 3;
      gload16(A + (size_t)(brow * 128 + r) * 512 + k0 + c * 8,
              Asl + (size_t)(rnd * 256 + wave * 64) * 8);
      gload16(Bw + (size_t)(bcol * 128 + r) * 512 + k0 + c * 8,
              Bsl + (size_t)(rnd * 256 + wave * 64) * 8);
    }
    __syncthreads();
    bf16x8 af[4], bfr[4];
#pragma unroll
    for (int m = 0; m < 4; ++m) af[m] = *(const bf16x8*)(Asl + (wm + m * 16 + l15) * 32 + lg * 8);
#pragma unroll
    for (int n = 0; n < 4; ++n) bfr[n] = *(const bf16x8*)(Bsl + (wn + n * 16 + l15) * 32 + lg * 8);
#pragma unroll
    for (int m = 0; m < 4; ++m)
#pragma unroll
      for (int n = 0; n < 4; ++n)
        acc[m][n] = __builtin_amdgcn_mfma_f32_16x16x32_bf16(af[m], bfr[n], acc[m][n], 0, 0, 0);
  }

  if (MODE == 0) {
    const int Nbase = bcol * 128;
    const int mat = Nbase >> 9;        // 0=q,1=k,2=v (uniform per block)
    const int colb = Nbase & 511;
    const float* bp = (mat == 0) ? b0 : ((mat == 1) ? b1 : b2);
#pragma unroll
    for (int m = 0; m < 4; ++m)
#pragma unroll
      for (int n = 0; n < 4; ++n) {
        const int col = colb + wn + n * 16 + l15;
        const int h = col >> 6, d = col & 63;
        const float bv = bp[col];
#pragma unroll
        for (int j = 0; j < 4; ++j) {
          const int M = brow * 128 + wm + m * 16 + lg * 4 + j;
          const int b = M >> 11, s = M & 2047;
          float outv = acc[m][n][j] + bv;
          if (mat == 0) outv *= 0.125f * LOG2E;  // softmax scale * log2e folded into q
          const unsigned short hv = f2bf(outv);
          if (mat == 0)
            oq[(((size_t)(b * Hh + h)) * Ss + s) * Dd + d] = hv;
          else if (mat == 1)
            ok[(((size_t)(b * Hh + h)) * Ss + s) * Dd + d] = hv;
          else
            ovt[(((size_t)(b * Hh + h)) * Dd + d) * Ss + s] = hv;  // V transposed
        }
      }
  } else {
#pragma unroll
    for (int m = 0; m < 4; ++m)
#pragma unroll
      for (int n = 0; n < 4; ++n) {
        const int col = bcol * 128 + wn + n * 16 + l15;
        const float bv = b0[col];
#pragma unroll
        for (int j = 0; j < 4; ++j) {
          const int M = brow * 128 + wm + m * 16 + lg * 4 + j;
          of32[(size_t)M * 512 + col] = acc[m][n][j] + bv;
        }
      }
  }
}

// ---------------- flash attention v5: r4 staging + swapped compute + bias pipeline ----
// grid (32,32), 4 waves x 16 q-rows. Lane: q = l15 (uniform), holds 16 key-scores.
// K,V staged via gload_lds dbuf (one barrier/iter, nothing else drains vmcnt mid-iter);
// bias prefetched one tile ahead into regs.
__global__ __launch_bounds__(256, 4) void k_attn(
    const unsigned short* __restrict__ q, const unsigned short* __restrict__ k,
    const unsigned short* __restrict__ vt, const unsigned short* __restrict__ mb,
    unsigned short* __restrict__ att) {
  __shared__ unsigned short Ksl[2][4096];  // [buf][ks][key64][d32]
  __shared__ unsigned short Vsl[2][4096];  // [buf][ks][d64][key32]
  __shared__ unsigned short Psl[4][1024];  // per-wave [16 q][64 key], XOR-swizzled
  const int tid = threadIdx.x;
  const int wave = tid >> 6, lane = tid & 63;
  const int l15 = lane & 15, lg = lane >> 4;
  const int qt = blockIdx.x, bh = blockIdx.y;
  const int b = bh >> 3, h = bh & 7;
  const size_t qkb = (size_t)bh * Ss * Dd;
  const size_t vtbase = (size_t)bh * Dd * Ss;
  const int q0 = qt * 64 + wave * 16;
  const int qrow = q0 + l15;
  const int swz = (l15 & 7) << 3;  // u16-index XOR (16B granules)

  bf16x8 qf[2];  // Q row (pre-scaled by 0.125*log2e)
#pragma unroll
  for (int ks = 0; ks < 2; ++ks)
    qf[ks] = *(const bf16x8*)(q + qkb + (size_t)qrow * Dd + ks * 32 + lg * 8);

  const size_t mbrow = ((size_t)b * Ss + qrow) * Ss;  // bias row base (log2-domain)

  f32x4 accO[4] = {};  // [d-block n][j]: d = n*16+lg*4+j, col q = l15
  float mrow = -INFINITY, lrow = 0.f;

  auto stage = [&](int buf, int t) {
    const int key0 = t * 64;
#pragma unroll
    for (int rnd = 0; rnd < 2; ++rnd) {
      int v2 = rnd * 256 + tid;
      int ks = v2 >> 8, r = (v2 >> 2) & 63, c = v2 & 3;
      gload16(k + qkb + (size_t)(key0 + r) * Dd + ks * 32 + c * 8,
              &Ksl[buf][(rnd * 256 + wave * 64) * 8]);
    }
#pragma unroll
    for (int rnd = 0; rnd < 2; ++rnd) {
      int v2 = rnd * 256 + tid;
      int ks = v2 >> 8, r = (v2 >> 2) & 63, c = v2 & 3;
      gload16(vt + vtbase + (size_t)r * Ss + key0 + ks * 32 + c * 8,
              &Vsl[buf][(rnd * 256 + wave * 64) * 8]);
    }
  };

  // prologue: stage tile 0, prefetch bias(0)
  stage(0, 0);
  u16x4 bvc[4], bvn[4];
#pragma unroll
  for (int m = 0; m < 4; ++m) bvc[m] = *(const u16x4*)(mb + mbrow + m * 16 + lg * 4);

  for (int t = 0; t < 32; ++t) {
    const int cur = t & 1;
    __syncthreads();  // tile t staged (vmcnt drained at barrier); buf reads done

    if (t < 31) {
      stage(cur ^ 1, t + 1);  // in flight across the whole compute phase
#pragma unroll
      for (int m = 0; m < 4; ++m)
        bvn[m] = *(const u16x4*)(mb + mbrow + (t + 1) * 64 + m * 16 + lg * 4);
    }

    // QK^T swapped: sc[m] rows = keys m*16+lg*4+j, col = q = l15
    f32x4 sc[4] = {};
#pragma unroll
    for (int ks = 0; ks < 2; ++ks) {
      bf16x8 kfm[4];
#pragma unroll
      for (int m = 0; m < 4; ++m)
        kfm[m] = *(const bf16x8*)(&Ksl[cur][ks * 2048 + (m * 16 + l15) * 32 + lg * 8]);
#pragma unroll
      for (int m = 0; m < 4; ++m)
        sc[m] = __builtin_amdgcn_mfma_f32_16x16x32_bf16(kfm[m], qf[ks], sc[m], 0, 0, 0);
    }

    // softmax (exp2 domain): bias from regs (prefetched last iter) -> zero wait
    float pm = -INFINITY;
#pragma unroll
    for (int m = 0; m < 4; ++m)
#pragma unroll
      for (int j = 0; j < 4; ++j) {
        sc[m][j] += bf2f(bvc[m][j]);
        pm = fmaxf(pm, sc[m][j]);
      }
    pm = fmaxf(pm, __shfl_xor(pm, 16));
    pm = fmaxf(pm, __shfl_xor(pm, 32));
    const float mnew = fmaxf(mrow, pm);
    const float c = exp2f(mrow - mnew);
    mrow = mnew;
    float rs = 0.f;
#pragma unroll
    for (int m = 0; m < 4; ++m)
#pragma unroll
      for (int j = 0; j < 4; ++j) {
        const float p = exp2f(sc[m][j] - mnew);
        sc[m][j] = p;
        rs += p;
      }
    rs += __shfl_xor(rs, 16);
    rs += __shfl_xor(rs, 32);
    lrow = lrow * c + rs;
#pragma unroll
    for (int n = 0; n < 4; ++n) accO[n] *= c;  // c uniform per lane

    // P -> LDS [q=l15][key], swizzled; 4x ds_write_b64
#pragma unroll
    for (int m = 0; m < 4; ++m) {
      u16x4 o;
#pragma unroll
      for (int j = 0; j < 4; ++j) o[j] = f2bf(sc[m][j]);
      *(u16x4*)(&Psl[wave][(l15 * 64 + m * 16 + lg * 4) ^ swz]) = o;
    }
    asm volatile("" ::: "memory");  // same-wave DS ops are in-order; pin program order

    // PV swapped: A = Vt[d][k] (LDS), B = P[k][q] (LDS); per ks: 1 b128 P + 4 b128 V + 4 MFMA
#pragma unroll
    for (int ks2 = 0; ks2 < 2; ++ks2) {
      bf16x8 pB = *(const bf16x8*)(&Psl[wave][(l15 * 64 + ks2 * 32 + lg * 8) ^ swz]);
      bf16x8 va[4];
#pragma unroll
      for (int n = 0; n < 4; ++n)
        va[n] = *(const bf16x8*)(&Vsl[cur][ks2 * 2048 + (n * 16 + l15) * 32 + lg * 8]);
#pragma unroll
      for (int n = 0; n < 4; ++n)
        accO[n] = __builtin_amdgcn_mfma_f32_16x16x32_bf16(va[n], pB, accO[n], 0, 0, 0);
    }

    // rotate bias pipeline
#pragma unroll
    for (int m = 0; m < 4; ++m) bvc[m] = bvn[m];
  }

  // epilogue: accO[n][j] = out[d = n*16+lg*4+j][q = l15]
  const float invl = 1.0f / lrow;
#pragma unroll
  for (int n = 0; n < 4; ++n) {
    u16x4 o;
#pragma unroll
    for (int j = 0; j < 4; ++j) o[j] = f2bf(accO[n][j] * invl);
    *(u16x4*)(att + ((size_t)b * Ss + qrow) * Ee + h * Dd + n * 16 + lg * 4) = o;
  }
}

extern "C" void kernel_launch(void* const* d_in, const int* in_sizes, int n_in,
                              void* d_out, int out_size, void* d_ws, size_t ws_size,
                              hipStream_t stream) {
  const float* x  = (const float*)d_in[0];
  const float* eb = (const float*)d_in[1];
  const int*   am = (const int*)d_in[2];
  const float* Wq = (const float*)d_in[3];
  const float* bq = (const float*)d_in[4];
  const float* Wk = (const float*)d_in[5];
  const float* bk = (const float*)d_in[6];
  const float* Wv = (const float*)d_in[7];
  const float* bv = (const float*)d_in[8];
  const float* Wo = (const float*)d_in[9];
  const float* bo = (const float*)d_in[10];
  float* out = (float*)d_out;

  unsigned short* xb   = (unsigned short*)d_ws;              // [8192][512]
  unsigned short* wqkv = xb + (size_t)8192 * 512;            // [1536][512]
  unsigned short* wo   = wqkv + (size_t)1536 * 512;          // [512][512]
  unsigned short* qb   = wo + (size_t)512 * 512;             // [B][H][S][D]
  unsigned short* kb   = qb + (size_t)Bb * Hh * Ss * Dd;     // [B][H][S][D]
  unsigned short* vtb  = kb + (size_t)Bb * Hh * Ss * Dd;     // [B][H][D][S]
  unsigned short* attb = vtb + (size_t)Bb * Hh * Ss * Dd;    // [8192][512]
  unsigned short* mbb  = attb + (size_t)8192 * 512;          // [B][S][S]

  k_cvt<<<4096, 256, 0, stream>>>(x, xb, 8192 * 512 / 4);
  k_cvt<<<256, 256, 0, stream>>>(Wq, wqkv, 512 * 512 / 4);
  k_cvt<<<256, 256, 0, stream>>>(Wk, wqkv + (size_t)512 * 512, 512 * 512 / 4);
  k_cvt<<<256, 256, 0, stream>>>(Wv, wqkv + (size_t)1024 * 512, 512 * 512 / 4);
  k_cvt<<<256, 256, 0, stream>>>(Wo, wo, 512 * 512 / 4);
  k_mb<<<16384, 256, 0, stream>>>(eb, am, mbb, Bb * Ss * Ss / 4);

  dim3 blk(256);
  dim3 g1(64, 12);
  k_gemm<0><<<g1, blk, 0, stream>>>(xb, wqkv, bq, bk, bv, qb, kb, vtb, nullptr);
  dim3 g2(32, 32);
  k_attn<<<g2, blk, 0, stream>>>(qb, kb, vtb, mbb, attb);
  dim3 g3(64, 4);
  k_gemm<1><<<g3, blk, 0, stream>>>(attb, wo, bo, nullptr, nullptr, nullptr, nullptr, nullptr, out);
}

// Round 8
// 181.093 us; speedup vs baseline: 1.5898x; 1.0307x over previous
//
#include <hip/hip_runtime.h>
#include <hip/hip_bf16.h>
#include <stdint.h>

#define DEV static __device__ __forceinline__

typedef float f32x4 __attribute__((ext_vector_type(4)));
typedef int   i32x4 __attribute__((ext_vector_type(4)));
typedef unsigned short u16x4 __attribute__((ext_vector_type(4)));
typedef unsigned u32x4 __attribute__((ext_vector_type(4)));
typedef __bf16 bf16x8 __attribute__((ext_vector_type(8)));

constexpr int Bb = 4, Ss = 2048, Ee = 512, Hh = 8, Dd = 64;
constexpr float LOG2E = 1.4426950408889634f;

DEV unsigned short f2bf(float f) {  // RNE f32->bf16
  unsigned u = __float_as_uint(f);
  u += 0x7fff + ((u >> 16) & 1);
  return (unsigned short)(u >> 16);
}
DEV float bf2f(unsigned short h) { return __uint_as_float(((unsigned)h) << 16); }

DEV unsigned cvtpk(float lo, float hi) {  // packed f32x2 -> bf16x2 (RNE)
  unsigned r;
  asm("v_cvt_pk_bf16_f32 %0, %1, %2" : "=v"(r) : "v"(lo), "v"(hi));
  return r;
}

DEV void gload16(const void* g, void* l) {
  __builtin_amdgcn_global_load_lds((__attribute__((address_space(1))) void*)(g),
                                   (__attribute__((address_space(3))) void*)(l), 16, 0, 0);
}

// ---------------- converts ----------------
__global__ void k_cvt(const float* __restrict__ src, unsigned short* __restrict__ dst, int n4) {
  int i = blockIdx.x * 256 + threadIdx.x;
  if (i >= n4) return;
  f32x4 v = *(const f32x4*)(src + (size_t)i * 4);
  u16x4 o;
#pragma unroll
  for (int j = 0; j < 4; ++j) o[j] = f2bf(v[j]);
  *(u16x4*)(dst + (size_t)i * 4) = o;
}

// bias*log2e, masked -> -1.44e38 (exp2-domain softmax)
__global__ void k_mb(const float* __restrict__ bias, const int* __restrict__ mask,
                     unsigned short* __restrict__ mb, int n4) {
  int i = blockIdx.x * 256 + threadIdx.x;
  if (i >= n4) return;
  f32x4 v = *(const f32x4*)(bias + (size_t)i * 4);
  i32x4 m = *(const i32x4*)(mask + (size_t)i * 4);
  u16x4 o;
  const unsigned short NEG = f2bf(-1e38f * LOG2E);
#pragma unroll
  for (int j = 0; j < 4; ++j) o[j] = m[j] ? f2bf(v[j] * LOG2E) : NEG;
  *(u16x4*)(mb + (size_t)i * 4) = o;
}

// ---------------- GEMM (A[M][512] x Bw[N][512]^T), 128x128 tile, BK=32 ----------------
template <int MODE>
__global__ __launch_bounds__(256) void k_gemm(
    const unsigned short* __restrict__ A, const unsigned short* __restrict__ Bw,
    const float* __restrict__ b0, const float* __restrict__ b1, const float* __restrict__ b2,
    unsigned short* __restrict__ oq, unsigned short* __restrict__ ok,
    unsigned short* __restrict__ ovt, float* __restrict__ of32) {
  __shared__ unsigned short Asl[128 * 32];
  __shared__ unsigned short Bsl[128 * 32];
  const int tid = threadIdx.x;
  const int wave = tid >> 6, lane = tid & 63;
  const int l15 = lane & 15, lg = lane >> 4;
  const int brow = blockIdx.x, bcol = blockIdx.y;
  const int wm = (wave >> 1) * 64, wn = (wave & 1) * 64;

  f32x4 acc[4][4] = {};

  for (int k0 = 0; k0 < 512; k0 += 32) {
    __syncthreads();
#pragma unroll
    for (int rnd = 0; rnd < 2; ++rnd) {
      int vid = rnd * 256 + tid;
      int r = vid >> 2, c = vid & 3;
      gload16(A + (size_t)(brow * 128 + r) * 512 + k0 + c * 8,
              Asl + (size_t)(rnd * 256 + wave * 64) * 8);
      gload16(Bw + (size_t)(bcol * 128 + r) * 512 + k0 + c * 8,
              Bsl + (size_t)(rnd * 256 + wave * 64) * 8);
    }
    __syncthreads();
    bf16x8 af[4], bfr[4];
#pragma unroll
    for (int m = 0; m < 4; ++m) af[m] = *(const bf16x8*)(Asl + (wm + m * 16 + l15) * 32 + lg * 8);
#pragma unroll
    for (int n = 0; n < 4; ++n) bfr[n] = *(const bf16x8*)(Bsl + (wn + n * 16 + l15) * 32 + lg * 8);
#pragma unroll
    for (int m = 0; m < 4; ++m)
#pragma unroll
      for (int n = 0; n < 4; ++n)
        acc[m][n] = __builtin_amdgcn_mfma_f32_16x16x32_bf16(af[m], bfr[n], acc[m][n], 0, 0, 0);
  }

  if (MODE == 0) {
    const int Nbase = bcol * 128;
    const int mat = Nbase >> 9;        // 0=q,1=k,2=v (uniform per block)
    const int colb = Nbase & 511;
    const float* bp = (mat == 0) ? b0 : ((mat == 1) ? b1 : b2);
#pragma unroll
    for (int m = 0; m < 4; ++m)
#pragma unroll
      for (int n = 0; n < 4; ++n) {
        const int col = colb + wn + n * 16 + l15;
        const int h = col >> 6, d = col & 63;
        const float bv = bp[col];
#pragma unroll
        for (int j = 0; j < 4; ++j) {
          const int M = brow * 128 + wm + m * 16 + lg * 4 + j;
          const int b = M >> 11, s = M & 2047;
          float outv = acc[m][n][j] + bv;
          if (mat == 0) outv *= 0.125f * LOG2E;  // softmax scale * log2e folded into q
          const unsigned short hv = f2bf(outv);
          if (mat == 0)
            oq[(((size_t)(b * Hh + h)) * Ss + s) * Dd + d] = hv;
          else if (mat == 1)
            ok[(((size_t)(b * Hh + h)) * Ss + s) * Dd + d] = hv;
          else
            ovt[(((size_t)(b * Hh + h)) * Dd + d) * Ss + s] = hv;  // V transposed
        }
      }
  } else {
#pragma unroll
    for (int m = 0; m < 4; ++m)
#pragma unroll
      for (int n = 0; n < 4; ++n) {
        const int col = bcol * 128 + wn + n * 16 + l15;
        const float bv = b0[col];
#pragma unroll
        for (int j = 0; j < 4; ++j) {
          const int M = brow * 128 + wm + m * 16 + lg * 4 + j;
          of32[(size_t)M * 512 + col] = acc[m][n][j] + bv;
        }
      }
  }
}

// ---------------- flash attention v6: reg-only P via cvt_pk + ds_bpermute ----------
// grid (32,32), 4 waves x 16 q-rows. Lane: q = l15 (uniform), holds 16 key-scores.
// LDS = K dbuf 16KB + V dbuf 16KB = 32KB -> 4 blocks/CU (16 waves).
// P redistribution: word w of pB[ks2] = Q[w][2ks2+(lg>>1)] from lane l15+32(lg&1)(+16).
__global__ __launch_bounds__(256, 4) void k_attn(
    const unsigned short* __restrict__ q, const unsigned short* __restrict__ k,
    const unsigned short* __restrict__ vt, const unsigned short* __restrict__ mb,
    unsigned short* __restrict__ att) {
  __shared__ unsigned short Ksl[2][4096];  // [buf][ks][key64][d32]
  __shared__ unsigned short Vsl[2][4096];  // [buf][ks][d64][key32]
  const int tid = threadIdx.x;
  const int wave = tid >> 6, lane = tid & 63;
  const int l15 = lane & 15, lg = lane >> 4;
  const int qt = blockIdx.x, bh = blockIdx.y;
  const int b = bh >> 3, h = bh & 7;
  const size_t qkb = (size_t)bh * Ss * Dd;
  const size_t vtbase = (size_t)bh * Dd * Ss;
  const int q0 = qt * 64 + wave * 16;
  const int qrow = q0 + l15;

  // bpermute byte-addresses (loop-invariant)
  const int addrA = (l15 + 32 * (lg & 1)) * 4;
  const int addrB = addrA + 64;
  const bool hi = (lg >> 1) != 0;  // selects m+1

  bf16x8 qf[2];  // Q row (pre-scaled by 0.125*log2e)
#pragma unroll
  for (int ks = 0; ks < 2; ++ks)
    qf[ks] = *(const bf16x8*)(q + qkb + (size_t)qrow * Dd + ks * 32 + lg * 8);

  const size_t mbrow = ((size_t)b * Ss + qrow) * Ss;  // bias row base (log2-domain)

  f32x4 accO[4] = {};  // [d-block n][j]: d = n*16+lg*4+j, col q = l15
  float mrow = -INFINITY, lrow = 0.f;

  auto stage = [&](int buf, int t) {
    const int key0 = t * 64;
#pragma unroll
    for (int rnd = 0; rnd < 2; ++rnd) {
      int v2 = rnd * 256 + tid;
      int ks = v2 >> 8, r = (v2 >> 2) & 63, c = v2 & 3;
      gload16(k + qkb + (size_t)(key0 + r) * Dd + ks * 32 + c * 8,
              &Ksl[buf][(rnd * 256 + wave * 64) * 8]);
    }
#pragma unroll
    for (int rnd = 0; rnd < 2; ++rnd) {
      int v2 = rnd * 256 + tid;
      int ks = v2 >> 8, r = (v2 >> 2) & 63, c = v2 & 3;
      gload16(vt + vtbase + (size_t)r * Ss + key0 + ks * 32 + c * 8,
              &Vsl[buf][(rnd * 256 + wave * 64) * 8]);
    }
  };

  // prologue: stage tile 0, prefetch bias(0)
  stage(0, 0);
  u16x4 bvc[4], bvn[4];
#pragma unroll
  for (int m = 0; m < 4; ++m) bvc[m] = *(const u16x4*)(mb + mbrow + m * 16 + lg * 4);

  for (int t = 0; t < 32; ++t) {
    const int cur = t & 1;
    __syncthreads();  // tile t staged (vmcnt drained at barrier); buf reads done

    if (t < 31) {
      stage(cur ^ 1, t + 1);  // in flight across the whole compute phase
#pragma unroll
      for (int m = 0; m < 4; ++m)
        bvn[m] = *(const u16x4*)(mb + mbrow + (t + 1) * 64 + m * 16 + lg * 4);
    }

    // QK^T swapped: sc[m] rows = keys m*16+lg*4+j, col = q = l15
    f32x4 sc[4] = {};
#pragma unroll
    for (int ks = 0; ks < 2; ++ks) {
      bf16x8 kfm[4];
#pragma unroll
      for (int m = 0; m < 4; ++m)
        kfm[m] = *(const bf16x8*)(&Ksl[cur][ks * 2048 + (m * 16 + l15) * 32 + lg * 8]);
#pragma unroll
      for (int m = 0; m < 4; ++m)
        sc[m] = __builtin_amdgcn_mfma_f32_16x16x32_bf16(kfm[m], qf[ks], sc[m], 0, 0, 0);
    }

    // softmax (exp2 domain): bias from regs (prefetched last iter)
    float pm = -INFINITY;
#pragma unroll
    for (int m = 0; m < 4; ++m)
#pragma unroll
      for (int j = 0; j < 4; ++j) {
        sc[m][j] += bf2f(bvc[m][j]);
        pm = fmaxf(pm, sc[m][j]);
      }
    pm = fmaxf(pm, __shfl_xor(pm, 16));
    pm = fmaxf(pm, __shfl_xor(pm, 32));
    const float mnew = fmaxf(mrow, pm);
    if (!__all(pm <= mrow)) {  // defer-rescale: skip when running max unchanged (wave-uniform)
      const float c = exp2f(mrow - mnew);
      lrow *= c;
#pragma unroll
      for (int n = 0; n < 4; ++n) accO[n] *= c;
    }
    mrow = mnew;
    float rs = 0.f;
#pragma unroll
    for (int m = 0; m < 4; ++m)
#pragma unroll
      for (int j = 0; j < 4; ++j) {
        const float p = exp2f(sc[m][j] - mnew);
        sc[m][j] = p;
        rs += p;
      }
    rs += __shfl_xor(rs, 16);
    rs += __shfl_xor(rs, 32);
    lrow += rs;

    // pack P -> bf16 pairs: Q[w][m] = pack(p[m][2w], p[m][2w+1])
    unsigned pk[4][2];
#pragma unroll
    for (int m = 0; m < 4; ++m) {
      pk[m][0] = cvtpk(sc[m][0], sc[m][1]);
      pk[m][1] = cvtpk(sc[m][2], sc[m][3]);
    }

    // PV: per ks2, pB via 8 bpermute + 4 cndmask; A = Vt[d][k] from LDS
#pragma unroll
    for (int ks2 = 0; ks2 < 2; ++ks2) {
      bf16x8 va[4];
#pragma unroll
      for (int n = 0; n < 4; ++n)
        va[n] = *(const bf16x8*)(&Vsl[cur][ks2 * 2048 + (n * 16 + l15) * 32 + lg * 8]);
      const int mlo = 2 * ks2, mhi = 2 * ks2 + 1;
      unsigned lo0 = __builtin_amdgcn_ds_bpermute(addrA, pk[mlo][0]);
      unsigned hi0 = __builtin_amdgcn_ds_bpermute(addrA, pk[mhi][0]);
      unsigned lo1 = __builtin_amdgcn_ds_bpermute(addrA, pk[mlo][1]);
      unsigned hi1 = __builtin_amdgcn_ds_bpermute(addrA, pk[mhi][1]);
      unsigned lo2 = __builtin_amdgcn_ds_bpermute(addrB, pk[mlo][0]);
      unsigned hi2 = __builtin_amdgcn_ds_bpermute(addrB, pk[mhi][0]);
      unsigned lo3 = __builtin_amdgcn_ds_bpermute(addrB, pk[mlo][1]);
      unsigned hi3 = __builtin_amdgcn_ds_bpermute(addrB, pk[mhi][1]);
      u32x4 wv;
      wv[0] = hi ? hi0 : lo0;
      wv[1] = hi ? hi1 : lo1;
      wv[2] = hi ? hi2 : lo2;
      wv[3] = hi ? hi3 : lo3;
      const bf16x8 pB = __builtin_bit_cast(bf16x8, wv);
#pragma unroll
      for (int n = 0; n < 4; ++n)
        accO[n] = __builtin_amdgcn_mfma_f32_16x16x32_bf16(va[n], pB, accO[n], 0, 0, 0);
    }

    // rotate bias pipeline
#pragma unroll
    for (int m = 0; m < 4; ++m) bvc[m] = bvn[m];
  }

  // epilogue: accO[n][j] = out[d = n*16+lg*4+j][q = l15]
  const float invl = 1.0f / lrow;
#pragma unroll
  for (int n = 0; n < 4; ++n) {
    u16x4 o;
#pragma unroll
    for (int j = 0; j < 4; ++j) o[j] = f2bf(accO[n][j] * invl);
    *(u16x4*)(att + ((size_t)b * Ss + qrow) * Ee + h * Dd + n * 16 + lg * 4) = o;
  }
}

extern "C" void kernel_launch(void* const* d_in, const int* in_sizes, int n_in,
                              void* d_out, int out_size, void* d_ws, size_t ws_size,
                              hipStream_t stream) {
  const float* x  = (const float*)d_in[0];
  const float* eb = (const float*)d_in[1];
  const int*   am = (const int*)d_in[2];
  const float* Wq = (const float*)d_in[3];
  const float* bq = (const float*)d_in[4];
  const float* Wk = (const float*)d_in[5];
  const float* bk = (const float*)d_in[6];
  const float* Wv = (const float*)d_in[7];
  const float* bv = (const float*)d_in[8];
  const float* Wo = (const float*)d_in[9];
  const float* bo = (const float*)d_in[10];
  float* out = (float*)d_out;

  unsigned short* xb   = (unsigned short*)d_ws;              // [8192][512]
  unsigned short* wqkv = xb + (size_t)8192 * 512;            // [1536][512]
  unsigned short* wo   = wqkv + (size_t)1536 * 512;          // [512][512]
  unsigned short* qb   = wo + (size_t)512 * 512;             // [B][H][S][D]
  unsigned short* kb   = qb + (size_t)Bb * Hh * Ss * Dd;     // [B][H][S][D]
  unsigned short* vtb  = kb + (size_t)Bb * Hh * Ss * Dd;     // [B][H][D][S]
  unsigned short* attb = vtb + (size_t)Bb * Hh * Ss * Dd;    // [8192][512]
  unsigned short* mbb  = attb + (size_t)8192 * 512;          // [B][S][S]

  k_cvt<<<4096, 256, 0, stream>>>(x, xb, 8192 * 512 / 4);
  k_cvt<<<256, 256, 0, stream>>>(Wq, wqkv, 512 * 512 / 4);
  k_cvt<<<256, 256, 0, stream>>>(Wk, wqkv + (size_t)512 * 512, 512 * 512 / 4);
  k_cvt<<<256, 256, 0, stream>>>(Wv, wqkv + (size_t)1024 * 512, 512 * 512 / 4);
  k_cvt<<<256, 256, 0, stream>>>(Wo, wo, 512 * 512 / 4);
  k_mb<<<16384, 256, 0, stream>>>(eb, am, mbb, Bb * Ss * Ss / 4);

  dim3 blk(256);
  dim3 g1(64, 12);
  k_gemm<0><<<g1, blk, 0, stream>>>(xb, wqkv, bq, bk, bv, qb, kb, vtb, nullptr);
  dim3 g2(32, 32);
  k_attn<<<g2, blk, 0, stream>>>(qb, kb, vtb, mbb, attb);
  dim3 g3(64, 4);
  k_gemm<1><<<g3, blk, 0, stream>>>(attb, wo, bo, nullptr, nullptr, nullptr, nullptr, nullptr, out);
}